// Round 1
// 713.449 us; speedup vs baseline: 1.0074x; 1.0074x over previous
//
#include <hip/hip_runtime.h>
#include <math.h>

#define NEXP 16
#define CAP  512
#define TTOK 1024
#define HDIM 2048
#define IDIM 1408
#define MAXR (TTOK*2)

typedef float fx4 __attribute__((ext_vector_type(4)));
typedef short short8 __attribute__((ext_vector_type(8)));
typedef unsigned int u32;
typedef unsigned long long u64;

__device__ __forceinline__ unsigned short f2bf(float f) {
    u32 u = __float_as_uint(f);
    u += 0x7FFFu + ((u >> 16) & 1u);       // round-to-nearest-even
    return (unsigned short)(u >> 16);
}
__device__ __forceinline__ u64 pack4bf(fx4 f) {
    u32 lo = (u32)f2bf(f.x) | ((u32)f2bf(f.y) << 16);
    u32 hi = (u32)f2bf(f.z) | ((u32)f2bf(f.w) << 16);
    return (u64)lo | ((u64)hi << 32);
}

// ---------------- router
__global__ void router_kernel(const float* __restrict__ logits,
                              int* __restrict__ topi, float* __restrict__ topw,
                              int* __restrict__ cnt1) {
    int t = blockIdx.x * blockDim.x + threadIdx.x;
    if (t >= TTOK) return;
    const float* l = logits + t * NEXP;
    float b0 = -INFINITY, b1 = -INFINITY; int i0 = 0, i1 = 0;
    for (int e = 0; e < NEXP; ++e) {
        float v = l[e];
        if (v > b0) { b1 = b0; i1 = i0; b0 = v; i0 = e; }
        else if (v > b1) { b1 = v; i1 = e; }
    }
    float w0 = 1.f / (1.f + expf(b1 - b0));
    topi[t*2]   = i0; topi[t*2+1] = i1;
    topw[t*2]   = w0; topw[t*2+1] = 1.f - w0;
    atomicAdd(&cnt1[i0], 1);
    atomicAdd(&cnt1[i1], 1);
}

__global__ void scan_kernel(const int* __restrict__ cnt1, int* __restrict__ base) {
    if (threadIdx.x == 0 && blockIdx.x == 0) {
        int s = 0;
        for (int e = 0; e < NEXP; ++e) {
            base[e] = s;
            int c = cnt1[e]; if (c > CAP) c = CAP;
            s += c;
        }
        base[NEXP] = s;
    }
}

__global__ void assign_kernel(const int* __restrict__ topi, const int* __restrict__ base,
                              int* __restrict__ cnt2,
                              int* __restrict__ slot_token, int* __restrict__ slot_of) {
    int t = blockIdx.x * blockDim.x + threadIdx.x;
    if (t >= TTOK) return;
    for (int k = 0; k < 2; ++k) {
        int e = topi[t*2+k];
        int p = atomicAdd(&cnt2[e], 1);
        if (p < CAP) {
            int s = base[e] + p;
            slot_token[s] = t;
            slot_of[t*2+k] = s;
        } else {
            slot_of[t*2+k] = -1;
        }
    }
}

// ---------------- pre-gather: A1[s] = bf16(x[slot_token[s]]), compact rows
__global__ void gather_kernel(const float* __restrict__ x,
                              const int* __restrict__ slot_token,
                              const int* __restrict__ base,
                              unsigned short* __restrict__ A1) {
    int s = blockIdx.x;
    if (s >= base[NEXP]) return;
    int t = slot_token[s];
    int c = threadIdx.x * 8;            // 256 threads x 8 = 2048
    const float* src = x + (size_t)t * HDIM + c;
    fx4 a = *(const fx4*)src, b = *(const fx4*)(src + 4);
    u64 v[2] = { pack4bf(a), pack4bf(b) };
    *(fx4*)&A1[(size_t)s * HDIM + c] = *(fx4*)v;
}

// ---------------- GEMM: 128(rows) x 128(cols) tile, BK=32, 8 waves (4M x 2N).
// FUSE=true : cols = 64 gate + 64 up paired -> silu epilogue, bf16 act out.
// FUSE=false: plain 128-col tile, fp32 out.
// Depth-4 register prefetch on W (HBM, ~900cy), depth-2 on A (L2-resident),
// LDS double buffer, one barrier per K-step.
#define LDA 40

template<int KDIM, bool FUSE>
__global__ __launch_bounds__(512, 4) void gemm_fused_kernel(
    const unsigned short* __restrict__ A,
    const float* __restrict__ W,
    unsigned short* __restrict__ act_out,
    float* __restrict__ y_out,
    const int* __restrict__ base)
{
    const int e = blockIdx.z;
    const int n0 = base[e];
    const int rows = base[e+1] - n0;
    const int rtile = blockIdx.y * 128;
    if (rtile >= rows) return;
    const int bx = blockIdx.x;

    __shared__ unsigned short sA[2][128 * LDA];
    __shared__ unsigned short sB[2][128 * LDA];

    const int tid  = threadIdx.x;
    const int lane = tid & 63;
    const int wv   = tid >> 6;
    const int wr   = wv & 3;          // wave row 0..3 (32 rows each)
    const int wc   = wv >> 2;         // wave col 0..1
    const int lr   = lane & 15;
    const int quad = lane >> 4;

    fx4 acc[2][4];
    #pragma unroll
    for (int i = 0; i < 2; ++i)
        #pragma unroll
        for (int j = 0; j < 4; ++j) acc[i][j] = (fx4)0.f;

    // staging decomposition: 512 threads
    const int ag = tid & 3, ar = tid >> 2;   // A: row ar(0..127), k-seg ag (8 bf16)
    const int bg = tid & 3, bc = tid >> 2;   // B: row bc(0..127), k-seg bg (8 fp32)

    const int agrow = rtile + ar;
    const bool aval = (agrow < rows);
    const unsigned short* Ap = A + (size_t)(aval ? (n0 + agrow) : n0) * KDIM + ag * 8;

    int brow;
    if (FUSE) brow = (bc < 64) ? (bx*64 + bc) : (IDIM + bx*64 + (bc - 64));
    else      brow = bx*128 + bc;
    const int NW = FUSE ? (2*IDIM) : HDIM;
    const float* Wp = W + ((size_t)e * NW + brow) * KDIM + bg * 8;

    fx4 pa[2];        // A prefetch, depth 2 (slot = iter & 1)
    fx4 pb[4][2];     // W prefetch, depth 4 (slot = iter & 3)

    auto prefA = [&](int s, int k0) {
        pa[s] = aval ? *(const fx4*)(Ap + k0) : (fx4)0.f;
    };
    auto prefB = [&](int s, int k0) {
        pb[s][0] = *(const fx4*)(Wp + k0);
        pb[s][1] = *(const fx4*)(Wp + k0 + 4);
    };
    auto stage = [&](int buf, int sa, int sb) {
        u64 v[2] = { pack4bf(pb[sb][0]), pack4bf(pb[sb][1]) };
        *(fx4*)&sB[buf][bc * LDA + bg * 8] = *(fx4*)v;
        *(fx4*)&sA[buf][ar * LDA + ag * 8] = pa[sa];
    };

    const int KT = KDIM / 32;

    prefA(0, 0);  prefB(0, 0);
    stage(0, 0, 0);
    prefA(1, 32);
    prefB(1, 32); prefB(2, 64); prefB(3, 96);
    __syncthreads();

    #pragma unroll 4
    for (int kt = 0; kt < KT; ++kt) {
        const int cur = kt & 1;
        if (kt + 2 < KT) prefA(cur,     (kt + 2) * 32);
        if (kt + 4 < KT) prefB(kt & 3,  (kt + 4) * 32);

        short8 af[2], bfr[4];
        #pragma unroll
        for (int mi = 0; mi < 2; ++mi)
            af[mi] = *(const short8*)&sA[cur][(wr*32 + mi*16 + lr) * LDA + quad*8];
        #pragma unroll
        for (int ni = 0; ni < 4; ++ni) {
            const int rb = FUSE ? ((ni < 2) ? (wc*32 + ni*16) : (64 + wc*32 + (ni-2)*16))
                                : (wc*64 + ni*16);
            bfr[ni] = *(const short8*)&sB[cur][(rb + lr) * LDA + quad*8];
        }
        #pragma unroll
        for (int mi = 0; mi < 2; ++mi)
            #pragma unroll
            for (int ni = 0; ni < 4; ++ni)
                acc[mi][ni] = __builtin_amdgcn_mfma_f32_16x16x32_bf16(
                    af[mi], bfr[ni], acc[mi][ni], 0, 0, 0);

        if (kt + 1 < KT) {
            stage(1 - cur, (kt + 1) & 1, (kt + 1) & 3);
            __syncthreads();
        }
    }

    // ---- epilogue. C/D layout: col = lane&15, row = quad*4 + reg
    if (FUSE) {
        #pragma unroll
        for (int mi = 0; mi < 2; ++mi) {
            #pragma unroll
            for (int nj = 0; nj < 2; ++nj) {
                const int col = bx*64 + wc*32 + nj*16 + lr;
                #pragma unroll
                for (int r = 0; r < 4; ++r) {
                    const int gr = rtile + wr*32 + mi*16 + quad*4 + r;
                    if (gr < rows) {
                        float g = acc[mi][nj][r];
                        float u = acc[mi][nj + 2][r];
                        float s = g / (1.f + __expf(-g)) * u;
                        act_out[(size_t)(n0 + gr) * IDIM + col] = f2bf(s);
                    }
                }
            }
        }
    } else {
        #pragma unroll
        for (int mi = 0; mi < 2; ++mi) {
            #pragma unroll
            for (int ni = 0; ni < 4; ++ni) {
                const int col = bx*128 + wc*64 + ni*16 + lr;
                #pragma unroll
                for (int r = 0; r < 4; ++r) {
                    const int gr = rtile + wr*32 + mi*16 + quad*4 + r;
                    if (gr < rows)
                        y_out[(size_t)(n0 + gr) * HDIM + col] = acc[mi][ni][r];
                }
            }
        }
    }
}

// ---------------- combine (single fp32 y buffer now)
__global__ void combine_kernel(const float* __restrict__ y,
                               const int* __restrict__ slot_of,
                               const float* __restrict__ topw,
                               float* __restrict__ out) {
    int t = blockIdx.x;
    int c = threadIdx.x * 8;
    int s0 = slot_of[t*2], s1 = slot_of[t*2+1];
    float w0 = topw[t*2], w1 = topw[t*2+1];
    float res[8];
    #pragma unroll
    for (int i = 0; i < 8; ++i) res[i] = 0.f;
    if (s0 >= 0) {
        const float* p = y + (size_t)s0 * HDIM + c;
        #pragma unroll
        for (int i = 0; i < 8; ++i) res[i] += w0 * p[i];
    }
    if (s1 >= 0) {
        const float* p = y + (size_t)s1 * HDIM + c;
        #pragma unroll
        for (int i = 0; i < 8; ++i) res[i] += w1 * p[i];
    }
    float* o = out + (size_t)t * HDIM + c;
    *(fx4*)o       = *(fx4*)res;
    *(fx4*)(o + 4) = *(fx4*)(res + 4);
}

extern "C" void kernel_launch(void* const* d_in, const int* in_sizes, int n_in,
                              void* d_out, int out_size, void* d_ws, size_t ws_size,
                              hipStream_t stream) {
    const float* x      = (const float*)d_in[0];
    const float* logits = (const float*)d_in[1];
    const float* w13    = (const float*)d_in[2];
    const float* w2     = (const float*)d_in[3];
    float* out = (float*)d_out;

    char* ws = (char*)d_ws;
    size_t off = 0;
    auto alloc = [&](size_t bytes) -> void* {
        void* p = ws + off;
        off += (bytes + 255) & ~(size_t)255;
        return p;
    };
    int*   topi       = (int*)  alloc(TTOK*2*sizeof(int));
    float* topw       = (float*)alloc(TTOK*2*sizeof(float));
    int*   cnt1       = (int*)  alloc(NEXP*sizeof(int));
    int*   cnt2       = (int*)  alloc(NEXP*sizeof(int));
    int*   base       = (int*)  alloc((NEXP+1)*sizeof(int));
    int*   slot_token = (int*)  alloc(TTOK*2*sizeof(int));
    int*   slot_of    = (int*)  alloc(TTOK*2*sizeof(int));
    unsigned short* A1  = (unsigned short*)alloc((size_t)MAXR * HDIM * 2);   // 8 MB
    unsigned short* act = (unsigned short*)alloc((size_t)MAXR * IDIM * 2);   // 5.8 MB
    float* ybuf = (float*)alloc((size_t)MAXR * HDIM * sizeof(float));        // 16.8 MB

    hipMemsetAsync(cnt1, 0, NEXP*sizeof(int), stream);
    hipMemsetAsync(cnt2, 0, NEXP*sizeof(int), stream);

    router_kernel<<<dim3((TTOK+255)/256), 256, 0, stream>>>(logits, topi, topw, cnt1);
    scan_kernel<<<1, 64, 0, stream>>>(cnt1, base);
    assign_kernel<<<dim3((TTOK+255)/256), 256, 0, stream>>>(topi, base, cnt2, slot_token, slot_of);
    gather_kernel<<<dim3(MAXR), 256, 0, stream>>>(x, slot_token, base, A1);

    // GEMM1 + fused silu: act = silu(A1 @ w13_gate^T) * (A1 @ w13_up^T)
    gemm_fused_kernel<HDIM, true>
        <<<dim3(IDIM/64, CAP/128, NEXP), 512, 0, stream>>>(A1, w13, act, nullptr, base);

    // GEMM2: ybuf = act @ w2^T  (fp32 out)
    gemm_fused_kernel<IDIM, false>
        <<<dim3(HDIM/128, CAP/128, NEXP), 512, 0, stream>>>(act, w2, nullptr, ybuf, base);

    combine_kernel<<<dim3(TTOK), 256, 0, stream>>>(ybuf, slot_of, topw, out);
}